// Round 8
// baseline (148.051 us; speedup 1.0000x reference)
//
#include <hip/hip_runtime.h>
#include <math.h>

#define BB 4
#define NSZ 2048
#define FDIM 128
#define ODIM 32
#define HH 8

typedef short short8 __attribute__((ext_vector_type(8)));
typedef float f32x4 __attribute__((ext_vector_type(4)));

// workspace layout (float units)
#define WS_EAP  0                 // float2[B*H*N] (EA, EA2)   = 131072 floats
#define WS_EBPK 131072            // u32[B*H*N] packed bf16 (EB,EB2) = 65536
#define WS_ADJB 196608            // u32[B*N*64]               = 524288 words
#define WS_WHF  720896            // bf16 Wh B-frags           = 1048576 floats (4MB)
// whf: int4[((b*H+h)*64 + jt)*2 + ot][64 lanes]

// round-to-nearest-even float -> bf16, result in TOP 16 bits
__device__ __forceinline__ unsigned bfbits(float f) {
    unsigned u = __builtin_bit_cast(unsigned, f);
    return u + 0x7fffu + ((u >> 16) & 1u);
}
// dword = (bf16(b) << 16) | bf16(a)
__device__ __forceinline__ unsigned bfpack(float a, float b) {
    return __builtin_amdgcn_perm(bfbits(b), bfbits(a), 0x07060302);
}

// ---------------------------------------------------------------------------
// Fused prep. Blocks [0,16384): adj bitmask pack (HBM stream).
// Blocks [16384,17408): MFMA projection for one (b,h,64 n-rows). W[h] staged
// per-block into padded LDS; Wh B-frags built in-block via LDS transpose.
// ebp now stored as ONE dword per node: packed bf16 (EB, EB2).
// ---------------------------------------------------------------------------
__global__ __launch_bounds__(256) void k_prep(const float* __restrict__ x,
                                              const float* __restrict__ adj,
                                              const float* __restrict__ W,
                                              const float* __restrict__ a_src,
                                              const float* __restrict__ a_dst,
                                              unsigned* __restrict__ adjb,
                                              int4* __restrict__ whf,
                                              float2* __restrict__ eap,
                                              unsigned* __restrict__ ebpk) {
    __shared__ float wsl[FDIM * 33];          // W[h] staged, row-padded (k*33+o)
    __shared__ unsigned short wlds[64][33];   // bf16 Wh tile [local n][o], +1 pad
    int t = threadIdx.x;

    if (blockIdx.x < 16384) {
        // ---------------- adj bitmask part ----------------
        int g = blockIdx.x * 256 + t;
        int l = g & 7;
        int word = g >> 3;
        int wk = word & 63;
        int row = word >> 6;
        int i = row & (NSZ - 1);
        const float4 v = *(const float4*)&adj[(size_t)row * NSZ + wk * 32 + l * 4];
        unsigned m = 0;
        if (v.x > 0.f) m |= 1u << (l * 4 + 0);
        if (v.y > 0.f) m |= 1u << (l * 4 + 1);
        if (v.z > 0.f) m |= 1u << (l * 4 + 2);
        if (v.w > 0.f) m |= 1u << (l * 4 + 3);
        m |= (unsigned)__shfl_xor((int)m, 1);
        m |= (unsigned)__shfl_xor((int)m, 2);
        m |= (unsigned)__shfl_xor((int)m, 4);
        if (l == 0) {
            int jb = i - wk * 32;
            if (jb >= 0 && jb < 32) m |= 1u << jb;  // self-loop
            adjb[word] = m;
        }
        return;
    }

    // ---------------- projection part ----------------
    int bidx = blockIdx.x - 16384;              // [0,1024): b(2) h(3) nt(5)
    int b = bidx >> 8;
    int h = (bidx >> 5) & 7;
    int nt = bidx & 31;
    int n0 = nt * 64;
    int w = t >> 6, lane = t & 63;
    int col = lane & 15, quad = lane >> 4;

    // stage W[h] (4096 floats) coalesced into padded LDS
#pragma unroll
    for (int m = 0; m < 16; m++) {
        int idx = t + m * 256;
        wsl[(idx >> 5) * 33 + (idx & 31)] = W[(size_t)h * (FDIM * ODIM) + idx];
    }

    // A-fragments: lane(quad,col) element j = x[b][n0+w*16+col][kt*32+quad*8+j]
    const float* xp = x + ((size_t)(b * NSZ) + n0 + w * 16 + col) * FDIM + quad * 8;
    int4 afr[4];
#pragma unroll
    for (int kt = 0; kt < 4; kt++) {
        float4 xa = *(const float4*)(xp + kt * 32);
        float4 xb = *(const float4*)(xp + kt * 32 + 4);
        afr[kt] = make_int4((int)bfpack(xa.x, xa.y), (int)bfpack(xa.z, xa.w),
                            (int)bfpack(xb.x, xb.y), (int)bfpack(xb.z, xb.w));
    }
    __syncthreads();

    // build W B-frags from LDS and run 8 MFMAs
    f32x4 alo = {0.f, 0.f, 0.f, 0.f};
    f32x4 ahi = {0.f, 0.f, 0.f, 0.f};
#pragma unroll
    for (int kt = 0; kt < 4; kt++) {
        short8 a8 = __builtin_bit_cast(short8, afr[kt]);
#pragma unroll
        for (int ot = 0; ot < 2; ot++) {
            unsigned d[4];
#pragma unroll
            for (int jp = 0; jp < 4; jp++) {
                float lo = wsl[(kt * 32 + quad * 8 + 2 * jp) * 33 + ot * 16 + col];
                float hi = wsl[(kt * 32 + quad * 8 + 2 * jp + 1) * 33 + ot * 16 + col];
                d[jp] = bfpack(lo, hi);
            }
            int4 bf = make_int4((int)d[0], (int)d[1], (int)d[2], (int)d[3]);
            if (ot == 0)
                alo = __builtin_amdgcn_mfma_f32_16x16x32_bf16(a8,
                        __builtin_bit_cast(short8, bf), alo, 0, 0, 0);
            else
                ahi = __builtin_amdgcn_mfma_f32_16x16x32_bf16(a8,
                        __builtin_bit_cast(short8, bf), ahi, 0, 0, 0);
        }
    }

    // alphas: reduce Wh[row]*a over o (col lanes), then exp factors
    float as0 = a_src[h * ODIM + col], as1 = a_src[h * ODIM + 16 + col];
    float ad0 = a_dst[h * ODIM + col], ad1 = a_dst[h * ODIM + 16 + col];
#pragma unroll
    for (int r = 0; r < 4; r++) {
        float pa = alo[r] * as0 + ahi[r] * as1;
        float pb = alo[r] * ad0 + ahi[r] * ad1;
#pragma unroll
        for (int mk = 1; mk <= 8; mk <<= 1) {
            pa += __shfl_xor(pa, mk);
            pb += __shfl_xor(pb, mk);
        }
        if (col == 0) {
            size_t idx = (size_t)(b * HH + h) * NSZ + n0 + w * 16 + quad * 4 + r;
            eap[idx] = make_float2(__expf(pa - 8.f), __expf(0.2f * pa - 8.f));
            float e1 = __expf(pb - 8.f);
            float e2 = __expf(0.2f * pb - 8.f);
            ebpk[idx] = (bfbits(e2) & 0xffff0000u) | (bfbits(e1) >> 16);
        }
    }

    // Wh -> LDS (bf16), then gather B-fragments: wave w does (jl=w>>1, ot=w&1)
#pragma unroll
    for (int r = 0; r < 4; r++) {
        wlds[w * 16 + quad * 4 + r][col]      = (unsigned short)(bfbits(alo[r]) >> 16);
        wlds[w * 16 + quad * 4 + r][col + 16] = (unsigned short)(bfbits(ahi[r]) >> 16);
    }
    __syncthreads();
    int jl = w >> 1, ot = w & 1;
    unsigned d[4];
#pragma unroll
    for (int jp = 0; jp < 4; jp++) {
        unsigned lo = wlds[jl * 32 + quad * 8 + 2 * jp][ot * 16 + col];
        unsigned hi = wlds[jl * 32 + quad * 8 + 2 * jp + 1][ot * 16 + col];
        d[jp] = (hi << 16) | lo;
    }
    int fragid = ((b * HH + h) * 64 + nt * 2 + jl) * 2 + ot;
    whf[(size_t)fragid * 64 + lane] = make_int4((int)d[0], (int)d[1], (int)d[2], (int)d[3]);
}

// masked p-fragment from PACKED bf16 eb pairs (one dword per j): unpack via
// shl/and (bf16-in-top-16 floats), mul/max, truncating perm pack, sext masks.
__device__ __forceinline__ int4 pfrag_pk(float eaa, float eab,
                                         const int4& ca, const int4& cb, unsigned w) {
    unsigned pd[8] = {(unsigned)ca.x, (unsigned)ca.y, (unsigned)ca.z, (unsigned)ca.w,
                      (unsigned)cb.x, (unsigned)cb.y, (unsigned)cb.z, (unsigned)cb.w};
    unsigned dw[4];
#pragma unroll
    for (int k = 0; k < 4; k++) {
        float e0  = __builtin_bit_cast(float, pd[2 * k] << 16);
        float e0b = __builtin_bit_cast(float, pd[2 * k] & 0xffff0000u);
        float e1  = __builtin_bit_cast(float, pd[2 * k + 1] << 16);
        float e1b = __builtin_bit_cast(float, pd[2 * k + 1] & 0xffff0000u);
        float pL = fmaxf(eaa * e0, eab * e0b);
        float pH = fmaxf(eaa * e1, eab * e1b);
        unsigned d = __builtin_amdgcn_perm(__builtin_bit_cast(unsigned, pH),
                                           __builtin_bit_cast(unsigned, pL), 0x07060302);
        int s0 = ((int)(w << (31 - 2 * k))) >> 31;
        int s1 = ((int)(w << (30 - 2 * k))) >> 31;
        unsigned mk = __builtin_amdgcn_perm((unsigned)s1, (unsigned)s0, 0x07060302);
        dw[k] = d & mk;
    }
    return make_int4((int)dw[0], (int)dw[1], (int)dw[2], (int)dw[3]);
}

// ---------------------------------------------------------------------------
// Fused masked-softmax aggregation. Block = (b,h,64 i-rows), 4 waves; wave =
// 16-jt quarter x all 4 i-frags (max B-frag/eb sharing: 12 MFMA per load set).
// K-loop is SOFTWARE-PIPELINED: jt+1's eb/whf/mask loads issue before jt's
// compute, so waitcnts are pre-satisfied (no barrier in the loop to drain).
// Single-stage combine: waves 1-3 dump to LDS, wave 0 sums + epilogue.
// ---------------------------------------------------------------------------
__global__ __launch_bounds__(256, 4) void k_gat(const int4* __restrict__ whf,
                                                const float2* __restrict__ eap,
                                                const unsigned* __restrict__ ebpk,
                                                const unsigned* __restrict__ adjb,
                                                float* __restrict__ out) {
    __shared__ float sbuf[9216];   // [0..2047]: packed eb; all 36KB: combine

    int t = threadIdx.x;
    int u = blockIdx.x;
    int unit = (u & 7) * 128 + (u >> 3);  // XCD swizzle
    int b = unit >> 8;
    int h = (unit >> 5) & 7;
    int i0 = (unit & 31) * 64;
    int wave = t >> 6, lane = t & 63;
    int col = lane & 15, quad = lane >> 4, qsh = quad * 8;
    size_t bh = (size_t)(b * HH + h);

    // stage packed eb table: 2048 dwords, coalesced
    unsigned* sbu = (unsigned*)sbuf;
    const uint4* ebg = (const uint4*)(ebpk + bh * NSZ);
    ((uint4*)sbu)[t] = ebg[t];
    ((uint4*)sbu)[t + 256] = ebg[t + 256];

    float2 ea[4];
    const unsigned* mr[4];
#pragma unroll
    for (int f = 0; f < 4; f++) {
        ea[f] = eap[bh * NSZ + i0 + f * 16 + col];
        mr[f] = adjb + ((size_t)(b * NSZ) + i0 + f * 16 + col) * 64;
    }
    const int4* bfp = whf + bh * 8192 + lane;

    f32x4 ac[4][3];   // [i-frag][0 = o 0..15, 1 = o 16..31, 2 = den]
#pragma unroll
    for (int f = 0; f < 4; f++)
#pragma unroll
        for (int c = 0; c < 3; c++) ac[f][c] = (f32x4){0.f, 0.f, 0.f, 0.f};
    const int4 onesv = make_int4(0x3F803F80, 0x3F803F80, 0x3F803F80, 0x3F803F80);
    short8 bones = __builtin_bit_cast(short8, onesv);

    __syncthreads();

    int jt0 = wave * 16;
    // rotating prefetch registers (cur)
    int4 c_e0 = ((const int4*)sbu)[jt0 * 8 + quad * 2];
    int4 c_e1 = ((const int4*)sbu)[jt0 * 8 + quad * 2 + 1];
    int4 c_b0 = bfp[jt0 * 128];
    int4 c_b1 = bfp[jt0 * 128 + 64];
    unsigned c_w0 = mr[0][jt0], c_w1 = mr[1][jt0], c_w2 = mr[2][jt0], c_w3 = mr[3][jt0];

    for (int s = 0; s < 16; s++) {
        // issue next iteration's loads (wraps to jt0 on last iter, harmless)
        int jn = jt0 + ((s + 1) & 15);
        int4 n_e0 = ((const int4*)sbu)[jn * 8 + quad * 2];
        int4 n_e1 = ((const int4*)sbu)[jn * 8 + quad * 2 + 1];
        int4 n_b0 = bfp[jn * 128];
        int4 n_b1 = bfp[jn * 128 + 64];
        unsigned n_w0 = mr[0][jn], n_w1 = mr[1][jn], n_w2 = mr[2][jn], n_w3 = mr[3][jn];

        short8 b0 = __builtin_bit_cast(short8, c_b0);
        short8 b1 = __builtin_bit_cast(short8, c_b1);
        unsigned cw[4] = {c_w0, c_w1, c_w2, c_w3};
#pragma unroll
        for (int f = 0; f < 4; f++) {
            int4 fr = pfrag_pk(ea[f].x, ea[f].y, c_e0, c_e1, cw[f] >> qsh);
            short8 a8 = __builtin_bit_cast(short8, fr);
            ac[f][0] = __builtin_amdgcn_mfma_f32_16x16x32_bf16(a8, b0, ac[f][0], 0, 0, 0);
            ac[f][1] = __builtin_amdgcn_mfma_f32_16x16x32_bf16(a8, b1, ac[f][1], 0, 0, 0);
            ac[f][2] = __builtin_amdgcn_mfma_f32_16x16x32_bf16(a8, bones, ac[f][2], 0, 0, 0);
        }

        c_e0 = n_e0; c_e1 = n_e1; c_b0 = n_b0; c_b1 = n_b1;
        c_w0 = n_w0; c_w1 = n_w1; c_w2 = n_w2; c_w3 = n_w3;
    }

    // ---- combine: waves 1-3 dump, wave 0 sums ----
    __syncthreads();                 // all eb reads done; sbuf reusable
    if (wave != 0) {
        f32x4* rg = (f32x4*)&sbuf[(wave - 1) * 3072];
#pragma unroll
        for (int f = 0; f < 4; f++)
#pragma unroll
            for (int c = 0; c < 3; c++) rg[(f * 3 + c) * 64 + lane] = ac[f][c];
    }
    __syncthreads();
    if (wave != 0) return;
#pragma unroll
    for (int wv = 0; wv < 3; wv++) {
        f32x4* rg = (f32x4*)&sbuf[wv * 3072];
#pragma unroll
        for (int f = 0; f < 4; f++)
#pragma unroll
            for (int c = 0; c < 3; c++) {
                f32x4 v = rg[(f * 3 + c) * 64 + lane];
#pragma unroll
                for (int r = 0; r < 4; r++) ac[f][c][r] += v[r];
            }
    }

    // epilogue: C/D layout col=lane&15, row=f*16+quad*4+reg; ac[f][2][r] = den
    float* op = out + ((size_t)(b * NSZ) + i0) * (HH * ODIM) + h * ODIM + col;
#pragma unroll
    for (int f = 0; f < 4; f++)
#pragma unroll
        for (int r = 0; r < 4; r++) {
            int row = f * 16 + quad * 4 + r;
            float inv = 1.0f / ac[f][2][r];
            op[(size_t)row * (HH * ODIM)]      = fmaxf(ac[f][0][r] * inv, 0.f);
            op[(size_t)row * (HH * ODIM) + 16] = fmaxf(ac[f][1][r] * inv, 0.f);
        }
}

extern "C" void kernel_launch(void* const* d_in, const int* in_sizes, int n_in,
                              void* d_out, int out_size, void* d_ws, size_t ws_size,
                              hipStream_t stream) {
    const float* x     = (const float*)d_in[0];
    const float* adj   = (const float*)d_in[1];
    const float* W     = (const float*)d_in[2];
    const float* a_src = (const float*)d_in[3];
    const float* a_dst = (const float*)d_in[4];
    float* out = (float*)d_out;

    float* ws = (float*)d_ws;
    float2* eap    = (float2*)(ws + WS_EAP);
    unsigned* ebpk = (unsigned*)(ws + WS_EBPK);
    unsigned* adjb = (unsigned*)(ws + WS_ADJB);
    int4* whf      = (int4*)(ws + WS_WHF);

    // fused prep: 16384 adj-bitmask blocks + 1024 MFMA-projection blocks
    k_prep<<<dim3(16384 + 1024), dim3(256), 0, stream>>>(x, adj, W, a_src, a_dst,
                                                         adjb, whf, eap, ebpk);
    // fused masked softmax + MFMA aggregation: 1024 blocks x 4 waves, pipelined
    k_gat<<<dim3(BB * HH * (NSZ / 64)), dim3(256), 0, stream>>>(whf, eap, ebpk, adjb, out);
}